// Round 1
// baseline (92.464 us; speedup 1.0000x reference)
//
#include <hip/hip_runtime.h>
#include <stdint.h>
#include <math.h>

#define NTH 256
#define SORT_MAX 2048
#define MAXK 50
#define FG_MAX 32
#define THRESH_F 0.05f
#define NMS_T 0.3f

// Decode one (image b, row n, class c) box exactly like the reference:
// bbox_transform_inv + clip + /scale.
__device__ __forceinline__ void decode_box(
    const float* __restrict__ rois, const float* __restrict__ pred,
    float H, float W, float scale,
    int b, int n, int c, int N, int C, float out[4])
{
    const float* r = rois + ((size_t)b * N + n) * 5;
    float bx1 = r[1], by1 = r[2], bx2 = r[3], by2 = r[4];
    float w  = bx2 - bx1 + 1.0f;
    float h  = by2 - by1 + 1.0f;
    float cx = bx1 + 0.5f * w;
    float cy = by1 + 0.5f * h;
    const float* d = pred + ((size_t)b * N + n) * 4 * C + 4 * c;
    float dx = d[0] * 0.1f, dy = d[1] * 0.1f;
    float dw = d[2] * 0.2f, dh = d[3] * 0.2f;
    float pcx = dx * w + cx;
    float pcy = dy * h + cy;
    float pw  = expf(dw) * w;
    float ph  = expf(dh) * h;
    float X1 = fminf(fmaxf(pcx - 0.5f * pw, 0.0f), W - 1.0f);
    float Y1 = fminf(fmaxf(pcy - 0.5f * ph, 0.0f), H - 1.0f);
    float X2 = fminf(fmaxf(pcx + 0.5f * pw, 0.0f), W - 1.0f);
    float Y2 = fminf(fmaxf(pcy + 0.5f * ph, 0.0f), H - 1.0f);
    out[0] = X1 / scale;
    out[1] = Y1 / scale;
    out[2] = X2 / scale;
    out[3] = Y2 / scale;
}

// Kernel 1: one block per (stream, image, fg-class).
// Collect valid candidates, sort desc by (score, then lower row first),
// decode boxes, greedy NMS with early stop at MAXK keeps.
// Outputs: kept scores (<=50), kept count, class-best (rank-0) box.
__global__ __launch_bounds__(NTH) void nms_kernel(
    const float* __restrict__ rois_A, const float* __restrict__ cls_A,
    const float* __restrict__ pred_A, const float* __restrict__ info_A,
    const float* __restrict__ rois_B, const float* __restrict__ cls_B,
    const float* __restrict__ pred_B, const float* __restrict__ info_B,
    int Bimg, int N, int C,
    float* __restrict__ kept_scores, int* __restrict__ kcounts,
    float* __restrict__ cls_box)
{
    const int FG = C - 1;
    const int bx = blockIdx.x;
    const int st  = bx / (Bimg * FG);
    const int rem = bx % (Bimg * FG);
    const int b = rem / FG;
    const int j = rem % FG;      // fg index
    const int c = j + 1;         // actual class (skip background)

    const float* rois = st ? rois_B : rois_A;
    const float* cls  = st ? cls_B  : cls_A;
    const float* pred = st ? pred_B : pred_A;
    const float* info = st ? info_B : info_A;

    __shared__ uint64_t keys[SORT_MAX];
    __shared__ float sx1[SORT_MAX], sy1[SORT_MAX], sx2[SORT_MAX], sy2[SORT_MAX];
    __shared__ float sar[SORT_MAX];
    __shared__ unsigned char sup[SORT_MAX];
    __shared__ int s_cnt, s_cur, s_kept, s_done;

    const int tid = threadIdx.x;
    if (tid == 0) s_cnt = 0;
    for (int i = tid; i < SORT_MAX; i += NTH) keys[i] = 0ull;
    __syncthreads();

    // Collect candidates with score > THRESH.
    for (int n = tid; n < N; n += NTH) {
        float sc = cls[((size_t)b * N + n) * C + c];
        if (sc > THRESH_F) {
            int p = atomicAdd(&s_cnt, 1);
            // key: score bits (positive -> monotonic) high, ~row low so that
            // descending sort gives score desc, row asc on ties.
            keys[p] = ((uint64_t)__float_as_uint(sc) << 32) |
                      (uint32_t)(~(uint32_t)n);
        }
    }
    __syncthreads();
    const int M = s_cnt;

    // Bitonic sort (descending) over next-pow2 >= M (padding keys are 0).
    if (M > 1) {
        int SN = 2;
        while (SN < M) SN <<= 1;
        for (int k = 2; k <= SN; k <<= 1) {
            for (int jj = k >> 1; jj > 0; jj >>= 1) {
                for (int i = tid; i < SN; i += NTH) {
                    int ix = i ^ jj;
                    if (ix > i) {
                        uint64_t a = keys[i], bb = keys[ix];
                        bool desc = ((i & k) == 0);
                        if (desc ? (a < bb) : (a > bb)) {
                            keys[i] = bb; keys[ix] = a;
                        }
                    }
                }
                __syncthreads();
            }
        }
    }

    // Decode boxes for the M sorted survivors.
    const float H = info[b * 3 + 0];
    const float W = info[b * 3 + 1];
    const float scale = info[b * 3 + 2];
    for (int i = tid; i < M; i += NTH) {
        uint32_t n = ~(uint32_t)(keys[i] & 0xffffffffull);
        float bxo[4];
        decode_box(rois, pred, H, W, scale, b, (int)n, c, N, C, bxo);
        sx1[i] = bxo[0]; sy1[i] = bxo[1]; sx2[i] = bxo[2]; sy2[i] = bxo[3];
        sar[i] = (bxo[2] - bxo[0] + 1.0f) * (bxo[3] - bxo[1] + 1.0f);
        sup[i] = 0;
    }
    if (tid == 0) { s_cur = 0; s_kept = 0; }
    __syncthreads();

    const size_t obase = (size_t)(st * Bimg + b) * FG + j;
    float* ksc = kept_scores + obase * MAXK;

    // Greedy NMS, early stop at MAXK keeps (sufficient for global top-50).
    while (true) {
        if (tid == 0) {
            int cur = s_cur;
            while (cur < M && sup[cur]) cur++;
            s_cur = cur;
            s_done = (cur >= M || s_kept >= MAXK) ? 1 : 0;
            if (!s_done) {
                ksc[s_kept] = __uint_as_float((uint32_t)(keys[cur] >> 32));
                s_kept++;
            }
        }
        __syncthreads();
        if (s_done) break;
        const int cur = s_cur;
        const float cx1 = sx1[cur], cy1 = sy1[cur];
        const float cx2 = sx2[cur], cy2 = sy2[cur], car = sar[cur];
        for (int i = cur + 1 + tid; i < M; i += NTH) {
            if (!sup[i]) {
                float ix1 = fmaxf(cx1, sx1[i]);
                float iy1 = fmaxf(cy1, sy1[i]);
                float ix2 = fminf(cx2, sx2[i]);
                float iy2 = fminf(cy2, sy2[i]);
                float iw = fmaxf(ix2 - ix1 + 1.0f, 0.0f);
                float ih = fmaxf(iy2 - iy1 + 1.0f, 0.0f);
                float inter = iw * ih;
                float iou = inter / (car + sar[i] - inter);
                if (iou > NMS_T) sup[i] = 1;
            }
        }
        if (tid == 0) s_cur = cur + 1;
        __syncthreads();
    }

    if (tid == 0) {
        kcounts[obase] = s_kept;
        float* cb = cls_box + obase * 4;
        if (M > 0) { cb[0] = sx1[0]; cb[1] = sy1[0]; cb[2] = sx2[0]; cb[3] = sy2[0]; }
        else       { cb[0] = 0.0f; cb[1] = 0.0f; cb[2] = 0.0f; cb[3] = 0.0f; }
    }
}

// Kernel 2: one block per (stream, image). Apply the global top-50 cap:
// class best is "in" iff fewer than 50 kept entries compare greater
// (score desc, then lower class on ties -- ranks provably irrelevant).
__global__ __launch_bounds__(128) void select_kernel(
    const float* __restrict__ kept_scores, const int* __restrict__ kcounts,
    const float* __restrict__ cls_box,
    const float* __restrict__ rois_A, const float* __restrict__ pred_A,
    const float* __restrict__ info_A,
    const float* __restrict__ rois_B, const float* __restrict__ pred_B,
    const float* __restrict__ info_B,
    int Bimg, int N, int C,
    float* __restrict__ best_s, float* __restrict__ best_b)
{
    const int FG = C - 1;
    const int bx = blockIdx.x;           // st*Bimg + b
    const int st = bx / Bimg;
    const int b  = bx % Bimg;
    const int tid = threadIdx.x;

    __shared__ float sk[FG_MAX][MAXK];
    __shared__ int   skc[FG_MAX];
    __shared__ float stopv[FG_MAX];
    __shared__ int   inflag[FG_MAX];
    __shared__ float gbox[4];

    const size_t base = (size_t)bx * FG;
    for (int i = tid; i < FG * MAXK; i += blockDim.x)
        sk[i / MAXK][i % MAXK] = kept_scores[base * MAXK + i];
    if (tid < FG) skc[tid] = kcounts[base + tid];
    __syncthreads();

    if (tid < FG) {
        const int cc = tid;
        const int kc = skc[cc];
        const float sc = (kc > 0) ? sk[cc][0] : -INFINITY;
        stopv[cc] = sc;
        int cnt = 0;
        if (kc > 0) {
            for (int c2 = 0; c2 < FG && cnt < MAXK; ++c2) {
                const int k2 = skc[c2];
                for (int k = 0; k < k2; ++k) {
                    const float v = sk[c2][k];
                    const bool greater = (v > sc) || (v == sc && c2 < cc);
                    if (!greater) break;   // lists are non-increasing
                    if (++cnt >= MAXK) break;
                }
            }
        }
        inflag[cc] = (kc > 0 && cnt < MAXK) ? 1 : 0;
    }
    __syncthreads();

    if (tid == 0) {
        // Global best kept detection = max over classes of class-best,
        // ties -> lower class. Fallback (no detections at all): decoded
        // box of row 0, class 1 (matches reference's stable-sort identity).
        int g = -1;
        float bs = -INFINITY;
        for (int c2 = 0; c2 < FG; ++c2)
            if (skc[c2] > 0 && stopv[c2] > bs) { bs = stopv[c2]; g = c2; }
        if (g >= 0) {
            const float* cb = cls_box + (base + g) * 4;
            gbox[0] = cb[0]; gbox[1] = cb[1]; gbox[2] = cb[2]; gbox[3] = cb[3];
        } else {
            const float* rois = st ? rois_B : rois_A;
            const float* pred = st ? pred_B : pred_A;
            const float* info = st ? info_B : info_A;
            decode_box(rois, pred, info[b * 3], info[b * 3 + 1], info[b * 3 + 2],
                       b, 0, 1, N, C, gbox);
        }
    }
    __syncthreads();

    if (tid < FG) {
        const int cc = tid;
        const int in = inflag[cc];
        best_s[base + cc] = in ? stopv[cc] : -INFINITY;
        float* ob = best_b + (base + cc) * 4;
        if (in) {
            const float* cb = cls_box + (base + cc) * 4;
            ob[0] = cb[0]; ob[1] = cb[1]; ob[2] = cb[2]; ob[3] = cb[3];
        } else {
            ob[0] = gbox[0]; ob[1] = gbox[1]; ob[2] = gbox[2]; ob[3] = gbox[3];
        }
    }
}

// Kernel 3: joint = sA * sB (IEEE: -inf*-inf=+inf preserved), first-max
// argmax, gather final boxes. Output = concat(box_A[8,4], box_B[8,4]).
__global__ __launch_bounds__(64) void combine_kernel(
    const float* __restrict__ best_s, const float* __restrict__ best_b,
    int Bimg, int FG, float* __restrict__ out)
{
    const int i = threadIdx.x;
    if (i >= Bimg) return;
    const float* sA = best_s + (size_t)i * FG;
    const float* sB = best_s + (size_t)(Bimg + i) * FG;
    float bj = 0.0f;
    int cls = 0;
    for (int c = 0; c < FG; ++c) {
        const float v = sA[c] * sB[c];
        if (c == 0 || v > bj) { bj = v; cls = c; }
    }
    const float* bA = best_b + ((size_t)i * FG + cls) * 4;
    const float* bB = best_b + ((size_t)(Bimg + i) * FG + cls) * 4;
    for (int k = 0; k < 4; ++k) {
        out[i * 4 + k]            = bA[k];
        out[Bimg * 4 + i * 4 + k] = bB[k];
    }
}

extern "C" void kernel_launch(void* const* d_in, const int* in_sizes, int n_in,
                              void* d_out, int out_size, void* d_ws, size_t ws_size,
                              hipStream_t stream) {
    const float* rois_A = (const float*)d_in[0];
    const float* cls_A  = (const float*)d_in[1];
    const float* pred_A = (const float*)d_in[2];
    const float* info_A = (const float*)d_in[3];
    const float* rois_B = (const float*)d_in[4];
    const float* cls_B  = (const float*)d_in[5];
    const float* pred_B = (const float*)d_in[6];
    const float* info_B = (const float*)d_in[7];
    float* out = (float*)d_out;

    const int Bimg = in_sizes[3] / 3;                  // 8
    const int N    = in_sizes[0] / (Bimg * 5);         // 2000
    const int C    = in_sizes[1] / (Bimg * N);         // 21
    const int FG   = C - 1;                            // 20
    const int NSB  = 2 * Bimg * FG;                    // 320 tasks

    // Workspace layout (bytes):
    char* ws = (char*)d_ws;
    float* kept_scores = (float*)ws;                       // [2][B][FG][50]
    size_t off = (size_t)NSB * MAXK * sizeof(float);
    int* kcounts = (int*)(ws + off);                       // [2][B][FG]
    off += (size_t)NSB * sizeof(int);
    float* cls_box = (float*)(ws + off);                   // [2][B][FG][4]
    off += (size_t)NSB * 4 * sizeof(float);
    float* best_s = (float*)(ws + off);                    // [2][B][FG]
    off += (size_t)NSB * sizeof(float);
    float* best_b = (float*)(ws + off);                    // [2][B][FG][4]

    nms_kernel<<<NSB, NTH, 0, stream>>>(
        rois_A, cls_A, pred_A, info_A,
        rois_B, cls_B, pred_B, info_B,
        Bimg, N, C, kept_scores, kcounts, cls_box);

    select_kernel<<<2 * Bimg, 128, 0, stream>>>(
        kept_scores, kcounts, cls_box,
        rois_A, pred_A, info_A, rois_B, pred_B, info_B,
        Bimg, N, C, best_s, best_b);

    combine_kernel<<<1, 64, 0, stream>>>(best_s, best_b, Bimg, FG, out);
}